// Round 1
// baseline (1886.244 us; speedup 1.0000x reference)
//
#include <hip/hip_runtime.h>

// aggregation_custom_12695923327642 — fused gated aggregation, fp32 baseline.
//
// Per edge e (D=128, P=2, PD=64):
//   gates[p][o] = clamp( sum_d e[p*64+d] * W[o][d], 0, 1 )     (o in 0..127)
//   out[o]      = e[o&63]*gates[0][o] + e[64+(o&63)]*gates[1][o]
//   contribution to node idx[e]:  x[e][o] + |lp| * out[o]      (single fused scatter)
//
// Design: block=256 = 2 edge-groups of 128 threads. Thread owns column o,
// holds W[o][0:64] in 64 VGPRs (loaded once per block). Edge vector staged in
// LDS; dot-product reads are wave-uniform ds_read_b128 broadcasts (conflict-
// free). 128 v_fma_f32 per thread per edge -> fp32 VALU floor ~333 us.
// Scatter: 128 coalesced global atomicAdd f32 per edge (205M total) — the
// measurement target of this round.

#define D  128
#define PD 64

__global__ __launch_bounds__(256, 4) void agg_gated_scatter_kernel(
    const float* __restrict__ x,
    const float* __restrict__ W,
    const float* __restrict__ lp_ptr,
    const int*  __restrict__ index,
    float* __restrict__ out,
    int E, int nIter)
{
    const int tid = threadIdx.x;
    const int g   = tid >> 7;        // edge-group 0/1 within block
    const int o   = tid & 127;       // output column this thread owns
    const int d0  = o & 63;

    __shared__ float sh_e[2][D];

    // --- W row o -> 64 VGPRs (W is [128,64] row-major, torch [out,in]) ---
    float w[PD];
    const float4* Wrow = reinterpret_cast<const float4*>(W + o * PD);
    #pragma unroll
    for (int i = 0; i < PD / 4; ++i) {
        float4 t = Wrow[i];
        w[4*i+0] = t.x; w[4*i+1] = t.y; w[4*i+2] = t.z; w[4*i+3] = t.w;
    }

    const float lp = fabsf(lp_ptr[0]);

    const long long groupCount = (long long)gridDim.x * 2;
    long long edge = (long long)blockIdx.x * 2 + g;

    for (int it = 0; it < nIter; ++it) {
        const bool active = (edge < (long long)E);
        float e_val = 0.0f;
        int   idx   = 0;
        if (active) {
            e_val = x[edge * D + o];     // coalesced: 128 threads, 512 B
            idx   = index[edge];         // wave-uniform load
            sh_e[g][o] = e_val;
        }
        __syncthreads();

        if (active) {
            // gates[0][o] = sum_d e[d]*w[d];  gates[1][o] = sum_d e[64+d]*w[d]
            const float4* sh4 = reinterpret_cast<const float4*>(&sh_e[g][0]);
            float acc0 = 0.0f, acc1 = 0.0f;
            #pragma unroll
            for (int i = 0; i < 16; ++i) {
                float4 ea = sh4[i];        // e[4i .. 4i+3]      (broadcast)
                float4 eb = sh4[16 + i];   // e[64+4i .. 64+4i+3](broadcast)
                acc0 = fmaf(ea.x, w[4*i+0], acc0);
                acc0 = fmaf(ea.y, w[4*i+1], acc0);
                acc0 = fmaf(ea.z, w[4*i+2], acc0);
                acc0 = fmaf(ea.w, w[4*i+3], acc0);
                acc1 = fmaf(eb.x, w[4*i+0], acc1);
                acc1 = fmaf(eb.y, w[4*i+1], acc1);
                acc1 = fmaf(eb.z, w[4*i+2], acc1);
                acc1 = fmaf(eb.w, w[4*i+3], acc1);
            }
            const float g0 = fminf(fmaxf(acc0, 0.0f), 1.0f);
            const float g1 = fminf(fmaxf(acc1, 0.0f), 1.0f);

            const float ep0 = sh_e[g][d0];        // e1[0][d]
            const float ep1 = sh_e[g][64 + d0];   // e1[1][d]
            const float v   = e_val + lp * (ep0 * g0 + ep1 * g1);

            atomicAdd(out + (long long)idx * D + o, v);  // coalesced 512 B burst
        }
        __syncthreads();   // protect sh_e before next iteration's overwrite
        edge += groupCount;
    }
}

extern "C" void kernel_launch(void* const* d_in, const int* in_sizes, int n_in,
                              void* d_out, int out_size, void* d_ws, size_t ws_size,
                              hipStream_t stream) {
    const float* x     = (const float*)d_in[0];
    const float* W     = (const float*)d_in[1];
    const float* lp    = (const float*)d_in[2];
    const int*   index = (const int*)d_in[3];
    float*       out   = (float*)d_out;

    const int E = in_sizes[0] / D;

    // d_out is poisoned 0xAA before every launch — zero it (async, capture-safe).
    hipMemsetAsync(d_out, 0, (size_t)out_size * sizeof(float), stream);

    const int block = 256;
    const int grid  = 2048;                       // grid-stride loop handles any E
    const long long groups = (long long)grid * 2; // 2 edge-groups per block
    const int nIter = (int)(((long long)E + groups - 1) / groups);

    agg_gated_scatter_kernel<<<grid, block, 0, stream>>>(x, W, lp, index, out, E, nIter);
}

// Round 2
// 1516.396 us; speedup vs baseline: 1.2439x; 1.2439x over previous
//
#include <hip/hip_runtime.h>

// aggregation_custom_12695923327642 — round 2: bf16 MFMA gate GEMM.
//
//   gates[e][p][o] = clamp( sum_d e1[e][p][d] * W[o][d], 0, 1 )
//   out[e][o]      = e1[e][0][o&63]*gates[e][0][o] + e1[e][1][o&63]*gates[e][1][o]
//   atomic scatter: out_node[idx[e]][o] += x[e][o] + |lp| * out[e][o]
//
// Structure: block=256 = 4 independent waves (no __syncthreads). Each wave
// processes 16-edge tiles: stage x (fp32) into padded LDS (stride 132 breaks
// 512B-stride bank aliasing), A-frags built from LDS with cvt->bf16, W held
// as 16 B-frags in VGPRs (loaded once). 2 M-tiles x 8 N-tiles x 2 k-steps =
// 32 MFMA per tile. C-layout (col=lane&15,row=quad*4+reg) puts both patches
// of an edge in the same lane (adjacent regs) -> combine is in-register.
// bf16 gate error is scaled by |lp|=1e-5 -> numerically invisible.

#define D   128
#define PD  64
#define EPW 16          // edges per wave-tile
#define RS  132         // padded LDS row stride (f32) — 132%32=4 banks shift/row

typedef float  f32x4  __attribute__((ext_vector_type(4)));
typedef __bf16 bf16x8 __attribute__((ext_vector_type(8)));

static __device__ __forceinline__ float clamp01(float v) {
    return fminf(fmaxf(v, 0.0f), 1.0f);   // v_med3_f32
}

__global__ __launch_bounds__(256, 3) void agg_mfma_kernel(
    const float* __restrict__ x,
    const float* __restrict__ W,
    const float* __restrict__ lp_ptr,
    const int*  __restrict__ index,
    float* __restrict__ out,
    int E, int nTiles)
{
    const int tid  = threadIdx.x;
    const int wave = tid >> 6;
    const int lane = tid & 63;
    const int q    = lane >> 4;     // quad 0..3
    const int c    = lane & 15;

    __shared__ float shx_all[4][EPW * RS];
    __shared__ int   shidx_all[4][EPW];
    float* shx   = shx_all[wave];
    int*   shidx = shidx_all[wave];

    // ---- B-frags: B[k][n] = W[o=n][d=k]; lane holds n=c, k=ks*32+q*8+j ----
    bf16x8 bfrag[8][2];
    #pragma unroll
    for (int nt = 0; nt < 8; ++nt) {
        #pragma unroll
        for (int ks = 0; ks < 2; ++ks) {
            const float* wp = W + (nt * 16 + c) * PD + ks * 32 + q * 8;
            f32x4 w0 = *(const f32x4*)(wp);
            f32x4 w1 = *(const f32x4*)(wp + 4);
            bf16x8 f;
            f[0] = (__bf16)w0[0]; f[1] = (__bf16)w0[1];
            f[2] = (__bf16)w0[2]; f[3] = (__bf16)w0[3];
            f[4] = (__bf16)w1[0]; f[5] = (__bf16)w1[1];
            f[6] = (__bf16)w1[2]; f[7] = (__bf16)w1[3];
            bfrag[nt][ks] = f;
        }
    }

    const float lp = fabsf(lp_ptr[0]);

    const int waveStride = gridDim.x * 4;
    for (int t = blockIdx.x * 4 + wave; t < nTiles; t += waveStride) {
        const long long e0 = (long long)t * EPW;
        const int remEdges = (int)((E - e0) < EPW ? (E - e0) : EPW);
        const int validV4  = remEdges * 32;      // valid float4 count in tile

        // ---- stage x tile: 16 edges x 128 f32, padded rows ----
        const float4* xg = (const float4*)(x + e0 * D);
        #pragma unroll
        for (int i = 0; i < 8; ++i) {
            const int v4 = lane + i * 64;
            float4 val = make_float4(0.f, 0.f, 0.f, 0.f);
            if (v4 < validV4) val = xg[v4];
            const int g4   = v4 * 4;
            const int edge = g4 >> 7;
            const int col  = g4 & 127;
            *(float4*)&shx[edge * RS + col] = val;
        }
        if (lane < EPW)
            shidx[lane] = (lane < remEdges) ? index[e0 + lane] : 0;
        // same wave produces & consumes LDS — compiler's lgkmcnt ordering suffices

        #pragma unroll
        for (int mt = 0; mt < 2; ++mt) {
            // ---- A-frags: A[m=c][k=ks*32+q*8+j] = e1[row>>1][row&1][k], row=mt*16+c
            const int rowl = mt * 16 + c;
            const int el   = rowl >> 1;
            const int p    = rowl & 1;
            bf16x8 afrag[2];
            #pragma unroll
            for (int ks = 0; ks < 2; ++ks) {
                const float* ap = &shx[el * RS + p * PD + ks * 32 + q * 8];
                f32x4 a0 = *(const f32x4*)(ap);
                f32x4 a1 = *(const f32x4*)(ap + 4);
                bf16x8 f;
                f[0] = (__bf16)a0[0]; f[1] = (__bf16)a0[1];
                f[2] = (__bf16)a0[2]; f[3] = (__bf16)a0[3];
                f[4] = (__bf16)a1[0]; f[5] = (__bf16)a1[1];
                f[6] = (__bf16)a1[2]; f[7] = (__bf16)a1[3];
                afrag[ks] = f;
            }

            f32x4 acc[8];
            #pragma unroll
            for (int nt = 0; nt < 8; ++nt) {
                acc[nt] = (f32x4){0.f, 0.f, 0.f, 0.f};
                acc[nt] = __builtin_amdgcn_mfma_f32_16x16x32_bf16(
                              afrag[0], bfrag[nt][0], acc[nt], 0, 0, 0);
                acc[nt] = __builtin_amdgcn_mfma_f32_16x16x32_bf16(
                              afrag[1], bfrag[nt][1], acc[nt], 0, 0, 0);
            }

            // ---- combine + scatter. C-layout: col=c (within N-tile),
            //      row = q*4 + reg  -> reg0,1 = edge eAl (p=0,1); reg2,3 = eBl.
            const int  eAl   = mt * 8 + q * 2;
            const int  eBl   = eAl + 1;
            const int  nodeA = shidx[eAl];
            const int  nodeB = shidx[eBl];
            const bool okA   = (e0 + eAl) < E;
            const bool okB   = (e0 + eBl) < E;
            float* outA = out + (long long)nodeA * D + c;
            float* outB = out + (long long)nodeB * D + c;

            #pragma unroll
            for (int dg = 0; dg < 4; ++dg) {
                const int d = dg * 16 + c;
                const float aA0 = shx[eAl * RS + d];        // e1[eA][0][d]
                const float aA1 = shx[eAl * RS + 64 + d];   // e1[eA][1][d]
                const float aB0 = shx[eBl * RS + d];
                const float aB1 = shx[eBl * RS + 64 + d];

                // N-tile dg   -> gate col gcol = dg*16+c      (chunk 0, x=aA0)
                // N-tile dg+4 -> gate col gcol = 64+dg*16+c   (chunk 1, x=aA1)
                const f32x4 g0 = acc[dg];
                const f32x4 g1 = acc[dg + 4];
                const float gA0 = clamp01(g0[0]), gA1 = clamp01(g0[1]);
                const float gB0 = clamp01(g0[2]), gB1 = clamp01(g0[3]);
                const float hA0 = clamp01(g1[0]), hA1 = clamp01(g1[1]);
                const float hB0 = clamp01(g1[2]), hB1 = clamp01(g1[3]);

                const float vA0 = aA0 + lp * (aA0 * gA0 + aA1 * gA1);
                const float vA1 = aA1 + lp * (aA0 * hA0 + aA1 * hA1);
                const float vB0 = aB0 + lp * (aB0 * gB0 + aB1 * gB1);
                const float vB1 = aB1 + lp * (aB0 * hB0 + aB1 * hB1);

                if (okA) {
                    atomicAdd(outA + dg * 16,      vA0);
                    atomicAdd(outA + 64 + dg * 16, vA1);
                }
                if (okB) {
                    atomicAdd(outB + dg * 16,      vB0);
                    atomicAdd(outB + 64 + dg * 16, vB1);
                }
            }
        }
    }
}

extern "C" void kernel_launch(void* const* d_in, const int* in_sizes, int n_in,
                              void* d_out, int out_size, void* d_ws, size_t ws_size,
                              hipStream_t stream) {
    const float* x     = (const float*)d_in[0];
    const float* W     = (const float*)d_in[1];
    const float* lp    = (const float*)d_in[2];
    const int*   index = (const int*)d_in[3];
    float*       out   = (float*)d_out;

    const int E      = in_sizes[0] / D;
    const int nTiles = (E + EPW - 1) / EPW;

    // d_out is poisoned 0xAA before every launch — zero it (capture-safe).
    hipMemsetAsync(d_out, 0, (size_t)out_size * sizeof(float), stream);

    int grid = (nTiles + 3) / 4;
    if (grid > 2560) grid = 2560;      // 10 blocks/CU worth of grid-stride
    agg_mfma_kernel<<<grid, 256, 0, stream>>>(x, W, lp, index, out, E, nTiles);
}